// Round 4
// baseline (93.216 us; speedup 1.0000x reference)
//
#include <hip/hip_runtime.h>

typedef __bf16 bf16x8 __attribute__((ext_vector_type(8)));
typedef float f32x4 __attribute__((ext_vector_type(4)));

static __device__ __forceinline__ unsigned int f2bf_rne(float f) {
  union { float f; unsigned int u; } v; v.f = f;
  return (v.u + 0x7FFFu + ((v.u >> 16) & 1u)) >> 16;
}

// ---- prep: W[f,d,e] -> bf16 retiled, AND zero d_out (poisoned 0xAA) -------
// layout: byte = d*32768 + (e>>5)*8192 + f*64 + ((e>>3)&3)*16 + (e&7)*2
//       = d-tile | e-phase chunk (8KB) | f row (64B) | e-group (16B) | e
__global__ void k_prep(const float* __restrict__ W, char* __restrict__ wt,
                       float4* __restrict__ out) {
  int t = blockIdx.x * 256 + threadIdx.x;     // 524288 threads
  if (t < 262144) out[t] = make_float4(0.f, 0.f, 0.f, 0.f);
  long i = (long)t * 4;                        // 2M W elements, 4/thread
  int f = (int)(i >> 14);
  int k = (int)(i & 16383);
  float4 w4 = *(const float4*)(W + i);
  int d = k >> 7, e = k & 127;
  unsigned int lo = f2bf_rne(w4.x) | (f2bf_rne(w4.y) << 16);
  unsigned int hi = f2bf_rne(w4.z) | (f2bf_rne(w4.w) << 16);
  long byo = (long)d * 32768 + (e >> 5) * 8192 + f * 64 + ((e >> 3) & 3) * 16 + (e & 7) * 2;
  unsigned int* dst = (unsigned int*)(wt + byo);
  dst[0] = lo; dst[1] = hi;
}

// ---- decayed prefix scan, 64-token chunks with 64-token lookback -----------
// (1.2^-64 ~ 8.5e-6 relative). Stored TRANSPOSED: st[e*8192 + (b*2048+t)]
__global__ void k_scan(const float* __restrict__ x, float* __restrict__ st) {
  int tid = blockIdx.x * 256 + threadIdx.x;   // 16384 threads
  int e  = tid & 127;
  int bc = tid >> 7;          // 0..127
  int b  = bc >> 5;
  int ch = bc & 31;
  int t0 = ch * 64;
  const float* xb = x + (long)b * 2048 * 128 + e;
  float* sb = st + (long)e * 8192 + b * 2048;
  const float inv = 1.0f / 1.2f;
  float c = 0.f;
  int ts = t0 - 64; if (ts < 0) ts = 0;
  for (int t = ts; t < t0; ++t) c = (c + xb[(long)t * 128]) * inv;
  for (int t = t0; t < t0 + 64; ++t) { sb[t] = c; c = (c + xb[(long)t * 128]) * inv; }
}

// ---------------- main: out[token,f] += sum_k (x[tok,d]*s[tok,e]) * W[f,k] --
// grid 256 = 64 token-tiles (BM=128) x K-split 4 -> exactly 1 block/CU; the 2
// XCDs sharing kq keep a 1MB W quarter L2-resident. 8 waves = f-half(ng) x
// e-phase(ep): DISJOINT (e,f) W slices -> W traffic 256MB total (vs 512 in
// R3), zero duplication. W streams global->VGPR (contiguous 1KB loads,
// register double-buffer); NO barriers in the K-loop.
__global__ __launch_bounds__(512, 2) void k_main(
    const float* __restrict__ x, const float* __restrict__ st,
    const char* __restrict__ wt, float* __restrict__ out) {
  __shared__ float red[128 * 128];     // 64KB epilogue reduction
  __shared__ float x_lds[128 * 36];    // 18KB x tile [128 tok][pad36]

  const int tid  = threadIdx.x;
  const int bid  = blockIdx.x;
  const int kq   = bid & 3;          // K-quarter: d in [kq*32, kq*32+32)
  const int tt   = bid >> 2;         // token tile (0..63)
  const int wv   = tid >> 6;
  const int ng   = wv & 1;           // f half
  const int ep   = wv >> 1;          // e-phase
  const int lane = tid & 63;
  const int r    = lane & 15;
  const int kg   = lane >> 4;
  const int tokenBase = tt * 128;

  // stage x tile [128 tokens][32 d-cols] (d = kq*32 + it)
  {
    int row = tid >> 2, c0 = (tid & 3) * 8;
    const float* src = x + (long)(tokenBase + row) * 128 + kq * 32 + c0;
    *(float4*)&x_lds[row * 36 + c0]     = *(const float4*)src;
    *(float4*)&x_lds[row * 36 + c0 + 4] = *(const float4*)(src + 4);
  }

  // s values: wave owns e = ep*32 + kg*8 + {0..7} for ALL d. 32 VGPRs packed.
  unsigned int sreg[8][4];
  {
    const float* stb = st + tokenBase + (long)(ep * 32 + kg * 8) * 8192;
    #pragma unroll
    for (int mr = 0; mr < 8; ++mr)
      #pragma unroll
      for (int jj = 0; jj < 4; ++jj) {
        const float* qp = stb + (long)(2 * jj) * 8192 + mr * 16 + r;
        sreg[mr][jj] = f2bf_rne(qp[0]) | (f2bf_rne(qp[8192]) << 16);
      }
  }
  __syncthreads();   // x_lds ready; only barrier before epilogue

  f32x4 acc[8][4];
  #pragma unroll
  for (int mr = 0; mr < 8; ++mr)
    #pragma unroll
    for (int n = 0; n < 4; ++n) acc[mr][n] = (f32x4){0.f, 0.f, 0.f, 0.f};

  const int loff = r * 64 + kg * 16;   // lane slot within (d, ep, ng) chunk
  const char* wtq = wt + (long)(kq * 32) * 32768 + ep * 8192 + ng * 4096;

#define AGEN(AOUT, IT)                                                    \
  {                                                                       \
    _Pragma("unroll")                                                     \
    for (int mr = 0; mr < 8; ++mr) {                                      \
      float xv = x_lds[(mr * 16 + r) * 36 + (IT)];                        \
      _Pragma("unroll")                                                   \
      for (int jj = 0; jj < 4; ++jj) {                                    \
        unsigned int u = sreg[mr][jj];                                    \
        float slo = __uint_as_float(u << 16);                             \
        float shi = __uint_as_float(u & 0xFFFF0000u);                     \
        AOUT[mr][jj * 2]     = (__bf16)(xv * slo);                        \
        AOUT[mr][jj * 2 + 1] = (__bf16)(xv * shi);                        \
      }                                                                   \
    }                                                                     \
  }
#define MFMAS(A, B)                                                       \
  {                                                                       \
    _Pragma("unroll")                                                     \
    for (int n = 0; n < 4; ++n)                                           \
      _Pragma("unroll")                                                   \
      for (int mr = 0; mr < 8; ++mr)                                      \
        acc[mr][n] = __builtin_amdgcn_mfma_f32_16x16x32_bf16(             \
            A[mr], B[n], acc[mr][n], 0, 0, 0);                            \
  }

  bf16x8 b0[4], b1[4], a[8];
  #pragma unroll
  for (int n = 0; n < 4; ++n) b0[n] = *(const bf16x8*)(wtq + n * 1024 + loff);

  #pragma unroll 1
  for (int it = 0; it < 32; it += 2) {
    {  // half A: prefetch it+1 -> b1, compute with b0
      const char* wn = wtq + (long)(it + 1) * 32768;
      #pragma unroll
      for (int n = 0; n < 4; ++n) b1[n] = *(const bf16x8*)(wn + n * 1024 + loff);
      AGEN(a, it);
      MFMAS(a, b0);
    }
    {  // half B: prefetch it+2 -> b0, compute with b1
      if (it + 2 < 32) {
        const char* wn = wtq + (long)(it + 2) * 32768;
        #pragma unroll
        for (int n = 0; n < 4; ++n) b0[n] = *(const bf16x8*)(wn + n * 1024 + loff);
      }
      AGEN(a, it + 1);
      MFMAS(a, b1);
    }
  }
#undef AGEN
#undef MFMAS

  // epilogue: reduce the 4 e-phase waves (per f-half) in LDS, then atomicAdd
  __syncthreads();
  #pragma unroll
  for (int round = 0; round < 4; ++round) {
    if (ep == round) {
      #pragma unroll
      for (int mr = 0; mr < 8; ++mr)
        #pragma unroll
        for (int n = 0; n < 4; ++n)
          #pragma unroll
          for (int q2 = 0; q2 < 4; ++q2) {
            int idx = (mr * 16 + kg * 4 + q2) * 128 + ng * 64 + n * 16 + r;
            if (round == 0) red[idx] = acc[mr][n][q2];
            else            red[idx] += acc[mr][n][q2];
          }
    }
    __syncthreads();
  }
  float* outp = out + (long)tokenBase * 128;
  #pragma unroll
  for (int j = 0; j < 32; ++j) {
    int idx = tid + j * 512;
    atomicAdd(&outp[idx], red[idx]);
  }
}

extern "C" void kernel_launch(void* const* d_in, const int* in_sizes, int n_in,
                              void* d_out, int out_size, void* d_ws, size_t ws_size,
                              hipStream_t stream) {
  const float* x = (const float*)d_in[0];        // [4,2048,128] f32
  const float* W = (const float*)d_in[1];        // [128,128,128] f32
  float* out = (float*)d_out;                    // [4,2048,128] f32
  float* st  = (float*)d_ws;                     // 4 MB: s transposed [e][token]
  char*  wt  = (char*)d_ws + (4 << 20);          // 4 MB: W bf16 retiled

  k_prep <<<dim3(2048), dim3(256), 0, stream>>>(W, wt, (float4*)out);
  k_scan <<<dim3(64),   dim3(256), 0, stream>>>(x, st);
  k_main <<<dim3(256),  dim3(512), 0, stream>>>(x, st, wt, out);
}

// Round 5
// 78.711 us; speedup vs baseline: 1.1843x; 1.1843x over previous
//
#include <hip/hip_runtime.h>

typedef _Float16 f16;
typedef _Float16 f16x2 __attribute__((ext_vector_type(2)));
typedef _Float16 f16x8 __attribute__((ext_vector_type(8)));
typedef float f32x4 __attribute__((ext_vector_type(4)));

static __device__ __forceinline__ unsigned int pk2(float lo, float hi) {
  union { f16 h[2]; unsigned int u; } v;
  v.h[0] = (f16)lo; v.h[1] = (f16)hi;
  return v.u;
}

// ---- fused prep: blocks 0..2047: W[f,d,e]->fp16 retile + zero out;
//      blocks 2048..2111: decayed prefix scan of x -> st (transposed).
// W layout: byte = d*32768 + (e>>5)*8192 + f*64 + ((e>>3)&3)*16 + (e&7)*2
// scan: s[b,0]=0; s[b,t]=(s[b,t-1]+x[b,t-1])/1.2; st[e*8192 + b*2048 + t];
//       64-token chunks with 64-token lookback (1.2^-64 ~ 8.5e-6 rel).
__global__ void k_pre(const float* __restrict__ W, char* __restrict__ wt,
                      float4* __restrict__ out, const float* __restrict__ x,
                      float* __restrict__ st) {
  int bid = blockIdx.x;
  if (bid < 2048) {
    int t = bid * 256 + threadIdx.x;           // 524288 threads
    if (t < 262144) out[t] = make_float4(0.f, 0.f, 0.f, 0.f);
    long i = (long)t * 4;                      // 2M W elements, 4/thread
    int f = (int)(i >> 14);
    int k = (int)(i & 16383);
    float4 w4 = *(const float4*)(W + i);
    int d = k >> 7, e = k & 127;
    long byo = (long)d * 32768 + (e >> 5) * 8192 + f * 64 + ((e >> 3) & 3) * 16 + (e & 7) * 2;
    unsigned int* dst = (unsigned int*)(wt + byo);
    dst[0] = pk2(w4.x, w4.y);
    dst[1] = pk2(w4.z, w4.w);
  } else {
    int tid = (bid - 2048) * 256 + threadIdx.x;   // 16384 threads
    int e  = tid & 127;
    int bc = tid >> 7;
    int b  = bc >> 5;
    int ch = bc & 31;
    int t0 = ch * 64;
    const float* xb = x + (long)b * 2048 * 128 + e;
    float* sb = st + (long)e * 8192 + b * 2048;
    const float inv = 1.0f / 1.2f;
    float c = 0.f;
    int ts = t0 - 64; if (ts < 0) ts = 0;
    for (int t = ts; t < t0; ++t) c = (c + xb[(long)t * 128]) * inv;
    for (int t = t0; t < t0 + 64; ++t) { sb[t] = c; c = (c + xb[(long)t * 128]) * inv; }
  }
}

// ---------------- main: out[token,f] += sum_k (x[tok,d]*s[tok,e]) * W[f,k] --
// grid 256 = 64 token-tiles (BM=128) x K-split 4 -> 1 block/CU. 8 waves =
// f-half(ng) x e-phase(ep), disjoint (e,f) W slices -> W traffic 256MB (L2).
// fp16 pipeline: A[token,k] = x*s via one v_pk_mul_f16 per 2 elements;
// per-mr AGEN immediately feeds its 4 MFMAs (MFMA pipe never waits on a
// full A-tile). B double-buffered in registers; no barriers in K-loop.
__global__ __launch_bounds__(512, 1) void k_main(
    const float* __restrict__ x, const float* __restrict__ st,
    const char* __restrict__ wt, float* __restrict__ out) {
  __shared__ float red[128 * 128];            // 64KB epilogue reduction
  __shared__ unsigned int x_lds[128 * 36];    // 18KB x tile [128 tok][pad36] half2(x,x)

  const int tid  = threadIdx.x;
  const int bid  = blockIdx.x;
  const int kq   = bid & 3;          // K-quarter: d in [kq*32, kq*32+32)
  const int tt   = bid >> 2;         // token tile (0..63)
  const int wv   = tid >> 6;
  const int ng   = wv & 1;           // f half
  const int ep   = wv >> 1;          // e-phase
  const int lane = tid & 63;
  const int r    = lane & 15;
  const int kg   = lane >> 4;
  const int tokenBase = tt * 128;

  // stage x tile as duplicated half2 (xv,xv), cols d = kq*32 + it
  {
    int row = tid >> 2, c0 = (tid & 3) * 8;
    const float* src = x + (long)(tokenBase + row) * 128 + kq * 32 + c0;
    float4 v0 = *(const float4*)src;
    float4 v1 = *(const float4*)(src + 4);
    unsigned int* dst = &x_lds[row * 36 + c0];
    dst[0] = pk2(v0.x, v0.x); dst[1] = pk2(v0.y, v0.y);
    dst[2] = pk2(v0.z, v0.z); dst[3] = pk2(v0.w, v0.w);
    dst[4] = pk2(v1.x, v1.x); dst[5] = pk2(v1.y, v1.y);
    dst[6] = pk2(v1.z, v1.z); dst[7] = pk2(v1.w, v1.w);
  }

  // s: wave owns e = ep*32 + kg*8 + {0..7} for ALL d; packed half2, 16 VGPRs.
  unsigned int sreg[8][4];
  {
    const float* stb = st + tokenBase + (long)(ep * 32 + kg * 8) * 8192;
    #pragma unroll
    for (int mr = 0; mr < 8; ++mr)
      #pragma unroll
      for (int jj = 0; jj < 4; ++jj) {
        const float* qp = stb + (long)(2 * jj) * 8192 + mr * 16 + r;
        sreg[mr][jj] = pk2(qp[0], qp[8192]);
      }
  }
  __syncthreads();   // x_lds ready; only barrier before epilogue

  f32x4 acc[8][4];
  #pragma unroll
  for (int mr = 0; mr < 8; ++mr)
    #pragma unroll
    for (int n = 0; n < 4; ++n) acc[mr][n] = (f32x4){0.f, 0.f, 0.f, 0.f};

  const int loff = r * 64 + kg * 16;   // lane slot within (d, ep, ng) 4KB chunk
  const char* wtq = wt + (long)(kq * 32) * 32768 + ep * 8192 + ng * 4096;

  // per-mr: 1 ds_read + 4 v_pk_mul_f16 -> 4 MFMAs immediately
#define STEP(BUF, IT)                                                       \
  {                                                                         \
    _Pragma("unroll")                                                       \
    for (int mr = 0; mr < 8; ++mr) {                                        \
      f16x2 xv2;                                                            \
      *(unsigned int*)&xv2 = x_lds[(mr * 16 + r) * 36 + (IT)];              \
      union { unsigned int u[4]; f16x8 v; } au;                             \
      _Pragma("unroll")                                                     \
      for (int jj = 0; jj < 4; ++jj) {                                      \
        f16x2 s2;                                                           \
        *(unsigned int*)&s2 = sreg[mr][jj];                                 \
        f16x2 p = xv2 * s2;                                                 \
        au.u[jj] = *(unsigned int*)&p;                                      \
      }                                                                     \
      _Pragma("unroll")                                                     \
      for (int n = 0; n < 4; ++n)                                           \
        acc[mr][n] = __builtin_amdgcn_mfma_f32_16x16x32_f16(                \
            au.v, BUF[n], acc[mr][n], 0, 0, 0);                             \
    }                                                                       \
  }

  f16x8 b0[4], b1[4];
  #pragma unroll
  for (int n = 0; n < 4; ++n) b0[n] = *(const f16x8*)(wtq + n * 1024 + loff);

  #pragma unroll 1
  for (int it = 0; it < 32; it += 2) {
    {  // half A: prefetch it+1 -> b1, compute it with b0
      const char* wn = wtq + (long)(it + 1) * 32768;
      #pragma unroll
      for (int n = 0; n < 4; ++n) b1[n] = *(const f16x8*)(wn + n * 1024 + loff);
      STEP(b0, it);
    }
    {  // half B: prefetch it+2 -> b0, compute it+1 with b1
      if (it + 2 < 32) {
        const char* wn = wtq + (long)(it + 2) * 32768;
        #pragma unroll
        for (int n = 0; n < 4; ++n) b0[n] = *(const f16x8*)(wn + n * 1024 + loff);
      }
      STEP(b1, it + 1);
    }
  }
#undef STEP

  // epilogue: reduce the 4 e-phase waves (per f-half) in LDS, then atomicAdd
  __syncthreads();
  #pragma unroll
  for (int round = 0; round < 4; ++round) {
    if (ep == round) {
      #pragma unroll
      for (int mr = 0; mr < 8; ++mr)
        #pragma unroll
        for (int n = 0; n < 4; ++n)
          #pragma unroll
          for (int q2 = 0; q2 < 4; ++q2) {
            int idx = (mr * 16 + kg * 4 + q2) * 128 + ng * 64 + n * 16 + r;
            if (round == 0) red[idx] = acc[mr][n][q2];
            else            red[idx] += acc[mr][n][q2];
          }
    }
    __syncthreads();
  }
  float* outp = out + (long)tokenBase * 128;
  #pragma unroll
  for (int j = 0; j < 32; ++j) {
    int idx = tid + j * 512;
    atomicAdd(&outp[idx], red[idx]);
  }
}

extern "C" void kernel_launch(void* const* d_in, const int* in_sizes, int n_in,
                              void* d_out, int out_size, void* d_ws, size_t ws_size,
                              hipStream_t stream) {
  const float* x = (const float*)d_in[0];        // [4,2048,128] f32
  const float* W = (const float*)d_in[1];        // [128,128,128] f32
  float* out = (float*)d_out;                    // [4,2048,128] f32
  float* st  = (float*)d_ws;                     // 4 MB: s transposed [e][token]
  char*  wt  = (char*)d_ws + (4 << 20);          // 4 MB: W fp16 retiled

  k_pre <<<dim3(2112), dim3(256), 0, stream>>>(W, wt, (float4*)out, x, st);
  k_main<<<dim3(256),  dim3(512), 0, stream>>>(x, st, wt, out);
}

// Round 6
// 65.528 us; speedup vs baseline: 1.4225x; 1.2012x over previous
//
#include <hip/hip_runtime.h>

typedef _Float16 f16;
typedef _Float16 f16x2 __attribute__((ext_vector_type(2)));
typedef _Float16 f16x8 __attribute__((ext_vector_type(8)));
typedef float f32x4 __attribute__((ext_vector_type(4)));

static __device__ __forceinline__ unsigned int pk2(float lo, float hi) {
  union { f16 h[2]; unsigned int u; } v;
  v.h[0] = (f16)lo; v.h[1] = (f16)hi;
  return v.u;
}

// ---- fused prep: blocks 0..2047: W[f,d,e]->fp16 retile + zero out;
//      blocks 2048..2111: decayed prefix scan of x -> st (transposed).
// W layout: byte = d*32768 + (e>>5)*8192 + f*64 + ((e>>3)&3)*16 + (e&7)*2
// scan: s[b,0]=0; s[b,t]=(s[b,t-1]+x[b,t-1])/1.2; st[e*8192 + b*2048 + t];
//       64-token chunks, 64-token lookback (1.2^-64 ~ 8.5e-6 rel), loops
//       have COMPILE-TIME bounds so loads batch (serial chain = FMAs only).
__global__ void k_pre(const float* __restrict__ W, char* __restrict__ wt,
                      float4* __restrict__ out, const float* __restrict__ x,
                      float* __restrict__ st) {
  int bid = blockIdx.x;
  if (bid < 2048) {
    int t = bid * 256 + threadIdx.x;           // 524288 threads
    if (t < 262144) out[t] = make_float4(0.f, 0.f, 0.f, 0.f);
    long i = (long)t * 4;                      // 2M W elements, 4/thread
    int f = (int)(i >> 14);
    int k = (int)(i & 16383);
    float4 w4 = *(const float4*)(W + i);
    int d = k >> 7, e = k & 127;
    long byo = (long)d * 32768 + (e >> 5) * 8192 + f * 64 + ((e >> 3) & 3) * 16 + (e & 7) * 2;
    unsigned int* dst = (unsigned int*)(wt + byo);
    dst[0] = pk2(w4.x, w4.y);
    dst[1] = pk2(w4.z, w4.w);
  } else {
    int tid = (bid - 2048) * 256 + threadIdx.x;   // 16384 threads
    int e  = tid & 127;
    int bc = tid >> 7;          // 0..127
    int b  = bc >> 5;
    int ch = bc & 31;           // 32 chunks of 64 tokens
    int t0 = ch * 64;
    const float* xb = x + (long)b * 2048 * 128 + e;
    float* sb = st + (long)e * 8192 + b * 2048;
    const float inv = 1.0f / 1.2f;
    float c = 0.f;
    if (ch > 0) {
      const float* xp = xb + (long)(t0 - 64) * 128;
      #pragma unroll
      for (int t = 0; t < 64; ++t) c = (c + xp[t * 128]) * inv;
    }
    const float* xq = xb + (long)t0 * 128;
    float* sq = sb + t0;
    #pragma unroll
    for (int t = 0; t < 64; ++t) { sq[t] = c; c = (c + xq[t * 128]) * inv; }
  }
}

// ---------------- main: out[token,f] += sum_k (x[tok,d]*s[tok,e]) * W[f,k] --
// grid 256 = 64 token-tiles (BM=128) x K-split 4 -> 1 block/CU; 2 XCDs share
// each 1MB W quarter (L2-resident). Block = 1024 thr = 16 waves =
// (token-half th x f-half ng x e-quadrant ep): disjoint W slices, traffic
// 256MB. Wave tile 64tok x 64f x 32e -> acc=64 AGPR; total regs ~126 ->
// 4 waves/SIMD (the TLP that R3-R5 never had). B global->VGPR dbuf,
// no barriers in the K-loop.
__global__ __launch_bounds__(1024, 4) void k_main(
    const float* __restrict__ x, const float* __restrict__ st,
    const char* __restrict__ wt, float* __restrict__ out) {
  __shared__ unsigned int x_lds[128 * 36];   // 18.4KB half2(x,x); offset 0
  __shared__ float red[128 * 129];           // 66KB padded epilogue reduction

  const int tid  = threadIdx.x;
  const int bid  = blockIdx.x;
  const int kq   = bid & 3;          // K-quarter: d in [kq*32, kq*32+32)
  const int tt   = bid >> 2;         // token tile (0..63)
  const int wv   = tid >> 6;         // 0..15
  const int lane = tid & 63;
  const int th   = wv & 1;           // token half
  const int ng   = (wv >> 1) & 1;    // f half
  const int ep   = wv >> 2;          // e quadrant (0..3)
  const int r    = lane & 15;
  const int kg   = lane >> 4;
  const int tokenBase = tt * 128;

  // stage x tile as duplicated half2 (xv,xv): [128 tok][pad36], cols d=kq*32+it
  {
    int row = tid >> 3, c0 = (tid & 7) * 4;
    const float* src = x + (long)(tokenBase + row) * 128 + kq * 32 + c0;
    float4 v0 = *(const float4*)src;
    unsigned int* dst = &x_lds[row * 36 + c0];
    dst[0] = pk2(v0.x, v0.x); dst[1] = pk2(v0.y, v0.y);
    dst[2] = pk2(v0.z, v0.z); dst[3] = pk2(v0.w, v0.w);
  }

  // s: wave owns e = ep*32 + kg*8 + {0..7} for ALL d; packed half2, 16 VGPRs.
  unsigned int sreg[4][4];
  {
    const float* stb = st + tokenBase + th * 64 + (long)(ep * 32 + kg * 8) * 8192;
    #pragma unroll
    for (int mr = 0; mr < 4; ++mr)
      #pragma unroll
      for (int jj = 0; jj < 4; ++jj) {
        const float* qp = stb + (long)(2 * jj) * 8192 + mr * 16 + r;
        sreg[mr][jj] = pk2(qp[0], qp[8192]);
      }
  }
  __syncthreads();   // x_lds ready; only barrier before epilogue

  f32x4 acc[4][4];
  #pragma unroll
  for (int mr = 0; mr < 4; ++mr)
    #pragma unroll
    for (int n = 0; n < 4; ++n) acc[mr][n] = (f32x4){0.f, 0.f, 0.f, 0.f};

  const int loff = r * 64 + kg * 16;   // lane slot within (d, ep, ng) 4KB chunk
  const char* wtq = wt + (long)(kq * 32) * 32768 + ep * 8192 + ng * 4096;

  // per-mr: 1 ds_read + 4 v_pk_mul_f16 -> its 4 MFMAs immediately
#define STEP(BUF, IT)                                                       \
  {                                                                         \
    _Pragma("unroll")                                                       \
    for (int mr = 0; mr < 4; ++mr) {                                        \
      f16x2 xv2;                                                            \
      *(unsigned int*)&xv2 = x_lds[(th * 64 + mr * 16 + r) * 36 + (IT)];    \
      union { unsigned int u[4]; f16x8 v; } au;                             \
      _Pragma("unroll")                                                     \
      for (int jj = 0; jj < 4; ++jj) {                                      \
        f16x2 s2;                                                           \
        *(unsigned int*)&s2 = sreg[mr][jj];                                 \
        f16x2 p = xv2 * s2;                                                 \
        au.u[jj] = *(unsigned int*)&p;                                      \
      }                                                                     \
      _Pragma("unroll")                                                     \
      for (int n = 0; n < 4; ++n)                                           \
        acc[mr][n] = __builtin_amdgcn_mfma_f32_16x16x32_f16(                \
            au.v, BUF[n], acc[mr][n], 0, 0, 0);                             \
    }                                                                       \
  }

  f16x8 b0[4], b1[4];
  #pragma unroll
  for (int n = 0; n < 4; ++n) b0[n] = *(const f16x8*)(wtq + n * 1024 + loff);

  #pragma unroll 1
  for (int it = 0; it < 32; it += 2) {
    const char* wn1 = wtq + (long)(it + 1) * 32768;
    #pragma unroll
    for (int n = 0; n < 4; ++n) b1[n] = *(const f16x8*)(wn1 + n * 1024 + loff);
    STEP(b0, it);
    if (it + 2 < 32) {
      const char* wn2 = wtq + (long)(it + 2) * 32768;
      #pragma unroll
      for (int n = 0; n < 4; ++n) b0[n] = *(const f16x8*)(wn2 + n * 1024 + loff);
    }
    STEP(b1, it + 1);
  }
#undef STEP

  // epilogue: reduce the 4 e-quadrant waves per (th, ng) in LDS, then atomicAdd
  __syncthreads();
  #pragma unroll
  for (int round = 0; round < 4; ++round) {
    if (ep == round) {
      #pragma unroll
      for (int mr = 0; mr < 4; ++mr)
        #pragma unroll
        for (int n = 0; n < 4; ++n)
          #pragma unroll
          for (int q2 = 0; q2 < 4; ++q2) {
            // C/D: col=lane&15 (f), row=kg*4+reg (token)
            int idx = (th * 64 + mr * 16 + kg * 4 + q2) * 129 + ng * 64 + n * 16 + r;
            if (round == 0) red[idx] = acc[mr][n][q2];
            else            red[idx] += acc[mr][n][q2];
          }
    }
    __syncthreads();
  }
  float* outp = out + (long)tokenBase * 128;
  #pragma unroll
  for (int j = 0; j < 16; ++j) {
    int row = (tid >> 7) + j * 8;
    int col = tid & 127;
    atomicAdd(&outp[row * 128 + col], red[row * 129 + col]);
  }
}

extern "C" void kernel_launch(void* const* d_in, const int* in_sizes, int n_in,
                              void* d_out, int out_size, void* d_ws, size_t ws_size,
                              hipStream_t stream) {
  const float* x = (const float*)d_in[0];        // [4,2048,128] f32
  const float* W = (const float*)d_in[1];        // [128,128,128] f32
  float* out = (float*)d_out;                    // [4,2048,128] f32
  float* st  = (float*)d_ws;                     // 4 MB: s transposed [e][token]
  char*  wt  = (char*)d_ws + (4 << 20);          // 4 MB: W fp16 retiled

  k_pre <<<dim3(2112), dim3(256),  0, stream>>>(W, wt, (float4*)out, x, st);
  k_main<<<dim3(256),  dim3(1024), 0, stream>>>(x, st, wt, out);
}

// Round 7
// 53.824 us; speedup vs baseline: 1.7319x; 1.2175x over previous
//
#include <hip/hip_runtime.h>

typedef _Float16 f16;
typedef _Float16 f16x2 __attribute__((ext_vector_type(2)));
typedef _Float16 f16x8 __attribute__((ext_vector_type(8)));
typedef float f32x4 __attribute__((ext_vector_type(4)));
typedef unsigned int u32;
typedef unsigned int u32x4 __attribute__((ext_vector_type(4)));

static __device__ __forceinline__ u32 pk2(float lo, float hi) {
  union { f16 h[2]; u32 u; } v;
  v.h[0] = (f16)lo; v.h[1] = (f16)hi;
  return v.u;
}

// ---- fused prep: blocks 0..2047: W[f,d,e]->fp16 retile;
//      blocks 2048..2111: decayed prefix scan of x -> st (transposed).
// W layout: byte = d*32768 + (e>>5)*8192 + f*64 + ((e>>3)&3)*16 + (e&7)*2
// scan: s[b,0]=0; s[b,t]=(s[b,t-1]+x[b,t-1])/1.2; st[e*8192 + b*2048 + t];
//       64-token chunks, 64-token lookback (1.2^-64 ~ 8.5e-6 rel).
__global__ void k_pre(const float* __restrict__ W, char* __restrict__ wt,
                      const float* __restrict__ x, float* __restrict__ st) {
  int bid = blockIdx.x;
  if (bid < 2048) {
    int t = bid * 256 + threadIdx.x;
    long i = (long)t * 4;                      // 2M W elements, 4/thread
    int f = (int)(i >> 14);
    int k = (int)(i & 16383);
    float4 w4 = *(const float4*)(W + i);
    int d = k >> 7, e = k & 127;
    long byo = (long)d * 32768 + (e >> 5) * 8192 + f * 64 + ((e >> 3) & 3) * 16 + (e & 7) * 2;
    u32* dst = (u32*)(wt + byo);
    dst[0] = pk2(w4.x, w4.y);
    dst[1] = pk2(w4.z, w4.w);
  } else {
    int tid = (bid - 2048) * 256 + threadIdx.x;   // 16384 threads
    int e  = tid & 127;
    int bc = tid >> 7;
    int b  = bc >> 5;
    int ch = bc & 31;
    int t0 = ch * 64;
    const float* xb = x + (long)b * 2048 * 128 + e;
    float* sb = st + (long)e * 8192 + b * 2048;
    const float inv = 1.0f / 1.2f;
    float c = 0.f;
    if (ch > 0) {
      const float* xp = xb + (long)(t0 - 64) * 128;
      #pragma unroll
      for (int t = 0; t < 64; ++t) c = (c + xp[t * 128]) * inv;
    }
    const float* xq = xb + (long)t0 * 128;
    float* sq = sb + t0;
    #pragma unroll
    for (int t = 0; t < 64; ++t) { sq[t] = c; c = (c + xq[t * 128]) * inv; }
  }
}

// ---- final reduce: out = sum over 4 K-split partials (no atomics) ----------
__global__ void k_red(const float4* __restrict__ part, float4* __restrict__ out) {
  int i = blockIdx.x * 256 + threadIdx.x;          // 262144 float4
  float4 a = part[i];
  float4 b = part[i + 262144];
  float4 c = part[i + 524288];
  float4 d = part[i + 786432];
  out[i] = make_float4(a.x + b.x + c.x + d.x, a.y + b.y + c.y + d.y,
                       a.z + b.z + c.z + d.z, a.w + b.w + c.w + d.w);
}

// ---------------- main: part[kq][token,f] = sum_{d in kq} (x*s) W ----------
// grid 256 = 64 token-tiles (BM=128) x K-split 4 -> 1 block/CU. 8 waves =
// f-half(ng) x e-quadrant(ep): DISJOINT W slices -> W traffic 256MB (L2).
// Inner loop runs register-only: x batched via one ds_read_b128 per mr per
// 4 d-steps; B ping-pong prefetched from global. No barriers in K-loop,
// no atomics (partials to workspace; k_red sums).
__global__ __launch_bounds__(512, 2) void k_main(
    const float* __restrict__ x, const float* __restrict__ st,
    const char* __restrict__ wt, float* __restrict__ part) {
  __shared__ u32 x_lds[128 * 36];        // 18KB half2(x,x) [128 tok][pad36]
  __shared__ float red[128 * 129];       // 66KB padded epilogue reduction

  const int tid  = threadIdx.x;
  const int bid  = blockIdx.x;
  const int kq   = bid & 3;          // K-quarter: d in [kq*32, kq*32+32)
  const int tt   = bid >> 2;         // token tile (0..63)
  const int wv   = tid >> 6;         // 0..7
  const int lane = tid & 63;
  const int ng   = wv & 1;           // f half
  const int ep   = wv >> 1;          // e quadrant
  const int r    = lane & 15;
  const int kg   = lane >> 4;
  const int tokenBase = tt * 128;

  // stage x tile as duplicated half2 (xv,xv): [128 tok][32 d], d = kq*32+it
  {
    int row = tid >> 2, c0 = (tid & 3) * 8;
    const float* src = x + (long)(tokenBase + row) * 128 + kq * 32 + c0;
    float4 v0 = *(const float4*)src;
    float4 v1 = *(const float4*)(src + 4);
    u32* dst = &x_lds[row * 36 + c0];
    dst[0] = pk2(v0.x, v0.x); dst[1] = pk2(v0.y, v0.y);
    dst[2] = pk2(v0.z, v0.z); dst[3] = pk2(v0.w, v0.w);
    dst[4] = pk2(v1.x, v1.x); dst[5] = pk2(v1.y, v1.y);
    dst[6] = pk2(v1.z, v1.z); dst[7] = pk2(v1.w, v1.w);
  }

  // s: wave owns e = ep*32 + kg*8 + {0..7} for ALL d; packed half2, 32 VGPRs.
  u32 sreg[8][4];
  {
    const float* stb = st + tokenBase + (long)(ep * 32 + kg * 8) * 8192;
    #pragma unroll
    for (int mr = 0; mr < 8; ++mr)
      #pragma unroll
      for (int jj = 0; jj < 4; ++jj) {
        const float* qp = stb + (long)(2 * jj) * 8192 + mr * 16 + r;
        sreg[mr][jj] = pk2(qp[0], qp[8192]);
      }
  }
  __syncthreads();   // x_lds ready; only barrier before epilogue

  f32x4 acc[8][4];
  #pragma unroll
  for (int mr = 0; mr < 8; ++mr)
    #pragma unroll
    for (int n = 0; n < 4; ++n) acc[mr][n] = (f32x4){0.f, 0.f, 0.f, 0.f};

  const int loff = r * 64 + kg * 16;   // lane slot within (d, ep, ng) 4KB chunk
  const char* wtq = wt + (long)(kq * 32) * 32768 + ep * 8192 + ng * 4096;

  // compute one d-step from registers only: xb word J feeds all 4 n-MFMAs
#define STEP(BUF, XB, J)                                                     \
  {                                                                          \
    _Pragma("unroll")                                                        \
    for (int mr = 0; mr < 8; ++mr) {                                         \
      f16x2 xv2;                                                             \
      *(u32*)&xv2 = XB[mr][J];                                               \
      union { u32 u[4]; f16x8 v; } au;                                       \
      _Pragma("unroll")                                                      \
      for (int jj = 0; jj < 4; ++jj) {                                       \
        f16x2 s2;                                                            \
        *(u32*)&s2 = sreg[mr][jj];                                           \
        f16x2 p = xv2 * s2;                                                  \
        au.u[jj] = *(u32*)&p;                                                \
      }                                                                      \
      _Pragma("unroll")                                                      \
      for (int n = 0; n < 4; ++n)                                            \
        acc[mr][n] = __builtin_amdgcn_mfma_f32_16x16x32_f16(                 \
            au.v, BUF[n], acc[mr][n], 0, 0, 0);                              \
    }                                                                        \
  }
#define BLOAD(BUF, IT)                                                       \
  {                                                                          \
    int itc = (IT) > 31 ? 31 : (IT);                                         \
    const char* wn = wtq + (long)itc * 32768;                                \
    _Pragma("unroll")                                                        \
    for (int n = 0; n < 4; ++n)                                              \
      BUF[n] = *(const f16x8*)(wn + n * 1024 + loff);                        \
  }

  f16x8 ba[4], bb[4];
  BLOAD(ba, 0);

  #pragma unroll 1
  for (int it4 = 0; it4 < 8; ++it4) {
    // batched x: one ds_read_b128 per mr covers 4 d-steps
    u32x4 xb[8];
    #pragma unroll
    for (int mr = 0; mr < 8; ++mr)
      xb[mr] = *(const u32x4*)&x_lds[(mr * 16 + r) * 36 + it4 * 4];
    int it = it4 * 4;
    BLOAD(bb, it + 1); STEP(ba, xb, 0);
    BLOAD(ba, it + 2); STEP(bb, xb, 1);
    BLOAD(bb, it + 3); STEP(ba, xb, 2);
    BLOAD(ba, it + 4); STEP(bb, xb, 3);
  }
#undef STEP
#undef BLOAD

  // epilogue: reduce the 4 e-quadrant waves (per f-half) in LDS, then store
  __syncthreads();
  #pragma unroll
  for (int round = 0; round < 4; ++round) {
    if (ep == round) {
      #pragma unroll
      for (int mr = 0; mr < 8; ++mr)
        #pragma unroll
        for (int n = 0; n < 4; ++n)
          #pragma unroll
          for (int q2 = 0; q2 < 4; ++q2) {
            // C/D: col=lane&15 (f), row=kg*4+reg (token)
            int idx = (mr * 16 + kg * 4 + q2) * 129 + ng * 64 + n * 16 + r;
            if (round == 0) red[idx] = acc[mr][n][q2];
            else            red[idx] += acc[mr][n][q2];
          }
    }
    __syncthreads();
  }
  // plain coalesced stores to this kq's private partial slice
  float* outp = part + (long)kq * 1048576 + (long)tokenBase * 128;
  #pragma unroll
  for (int j = 0; j < 32; ++j) {
    int row = (tid >> 7) + j * 4;
    int col = tid & 127;
    outp[row * 128 + col] = red[row * 129 + col];
  }
}

extern "C" void kernel_launch(void* const* d_in, const int* in_sizes, int n_in,
                              void* d_out, int out_size, void* d_ws, size_t ws_size,
                              hipStream_t stream) {
  const float* x = (const float*)d_in[0];        // [4,2048,128] f32
  const float* W = (const float*)d_in[1];        // [128,128,128] f32
  float* out  = (float*)d_out;                   // [4,2048,128] f32
  float* st   = (float*)d_ws;                    // 4 MB: s transposed [e][token]
  char*  wt   = (char*)d_ws + (4 << 20);         // 4 MB: W fp16 retiled
  float* part = (float*)((char*)d_ws + (8 << 20)); // 16 MB: K-split partials

  k_pre <<<dim3(2112), dim3(256), 0, stream>>>(W, wt, x, st);
  k_main<<<dim3(256),  dim3(512), 0, stream>>>(x, st, wt, part);
  k_red <<<dim3(1024), dim3(256), 0, stream>>>((const float4*)part, (float4*)out);
}